// Round 7
// baseline (721.791 us; speedup 1.0000x reference)
//
#include <hip/hip_runtime.h>

#define HID 128

using short8  = __attribute__((ext_vector_type(8))) short;
using float4v = __attribute__((ext_vector_type(4))) float;

// ---- fp32 -> bf16 (RNE) helpers ----
__device__ __forceinline__ unsigned short f2bf(float f) {
    unsigned u = __float_as_uint(f);
    u = u + 0x7fff + ((u >> 16) & 1);
    return (unsigned short)(u >> 16);
}
__device__ __forceinline__ float bf2f(unsigned short h) {
    return __uint_as_float(((unsigned)h) << 16);
}
__device__ __forceinline__ void split2(float x, unsigned short& hi, unsigned short& lo) {
    hi = f2bf(x);
    lo = f2bf(x - bf2f(hi));
}

// ---------------- CSR build ----------------

__global__ void deg_int_kernel(const int* __restrict__ dst, int* __restrict__ degi, int E) {
    int i = blockIdx.x * blockDim.x + threadIdx.x;
    if (i < E) atomicAdd(&degi[dst[i]], 1);
}

__global__ __launch_bounds__(1024) void scan1_kernel(
    const int* __restrict__ in, int* __restrict__ incl, int* __restrict__ bsums, int N) {
    __shared__ int sm[1024];
    int i = blockIdx.x * 1024 + threadIdx.x;
    int v = (i < N) ? in[i] : 0;
    sm[threadIdx.x] = v;
    __syncthreads();
    for (int off = 1; off < 1024; off <<= 1) {
        int t = (threadIdx.x >= (unsigned)off) ? sm[threadIdx.x - off] : 0;
        __syncthreads();
        sm[threadIdx.x] += t;
        __syncthreads();
    }
    if (i < N) incl[i] = sm[threadIdx.x];
    if (threadIdx.x == 1023) bsums[blockIdx.x] = sm[1023];
}

__global__ __launch_bounds__(1024) void scan2_kernel(int* __restrict__ bsums, int nblk) {
    __shared__ int sm[1024];
    int t = threadIdx.x;
    int v = (t < nblk) ? bsums[t] : 0;
    sm[t] = v;
    __syncthreads();
    for (int off = 1; off < 1024; off <<= 1) {
        int u = (t >= (unsigned)off) ? sm[t - off] : 0;
        __syncthreads();
        sm[t] += u;
        __syncthreads();
    }
    if (t < nblk) bsums[t] = sm[t] - v;  // exclusive
}

__global__ void scan3_kernel(const int* __restrict__ incl, const int* __restrict__ degi,
                             const int* __restrict__ bsums, int* __restrict__ rowptr,
                             int* __restrict__ cursor, float* __restrict__ dinv, int N, int E) {
    int i = blockIdx.x * blockDim.x + threadIdx.x;
    if (i < N) {
        int r = bsums[i >> 10] + incl[i] - degi[i];
        rowptr[i] = r;
        cursor[i] = r;
        dinv[i] = rsqrtf((float)degi[i] + 1.0f);
    }
    if (i == 0) rowptr[N] = E;
}

__global__ void fill_kernel(const int* __restrict__ src, const int* __restrict__ dst,
                            int* __restrict__ cursor, int* __restrict__ col, int E) {
    int e = blockIdx.x * blockDim.x + threadIdx.x;
    if (e < E) {
        int d = dst[e];
        int pos = atomicAdd(&cursor[d], 1);
        col[pos] = src[e];
    }
}

// ---------------- input / weight conversion ----------------

__global__ void xsplit_kernel(const float* __restrict__ x, unsigned short* __restrict__ Xhi,
                              unsigned short* __restrict__ Xlo, int total4) {
    int i = blockIdx.x * blockDim.x + threadIdx.x;
    if (i >= total4) return;
    const float4 v = *(const float4*)(x + (size_t)i * 4);
    ushort4 h, l;
    split2(v.x, h.x, l.x);
    split2(v.y, h.y, l.y);
    split2(v.z, h.z, l.z);
    split2(v.w, h.w, l.w);
    *(ushort4*)(Xhi + (size_t)i * 4) = h;
    *(ushort4*)(Xlo + (size_t)i * 4) = l;
}

// all 5 weight matrices transposed+split in one dispatch
struct WSegs {
    const float* W[5];
    unsigned short* hi[5];
    unsigned short* lo[5];
    int K[5], M[5], start[5];
};

__global__ void wsplit_all_kernel(WSegs S, int total) {
    int idx = blockIdx.x * blockDim.x + threadIdx.x;
    if (idx >= total) return;
    int s = 0;
#pragma unroll
    for (int t = 1; t < 5; ++t)
        if (idx >= S.start[t]) s = t;
    int local = idx - S.start[s];
    int M = S.M[s], K = S.K[s];
    int k = local / M;
    int m = local - k * M;
    unsigned short hi, lo;
    split2(S.W[s][local], hi, lo);
    S.hi[s][(size_t)m * K + k] = hi;
    S.lo[s][(size_t)m * K + k] = lo;
}

// ---------------- fused gather-reduce + finalize -> split planes ----------------
__global__ __launch_bounds__(256) void gather_kernel(
    const float* __restrict__ hs, const int* __restrict__ rowptr,
    const int* __restrict__ col, const float* __restrict__ dinv,
    const float* __restrict__ bias, unsigned short* __restrict__ Chi,
    unsigned short* __restrict__ Clo, int N) {
    long long idx = (long long)blockIdx.x * blockDim.x + threadIdx.x;
    int i = (int)(idx >> 5);
    if (i >= N) return;
    int c = ((int)idx & 31) * 4;

    int beg = rowptr[i];
    int end = rowptr[i + 1];

    float4 acc = *(const float4*)(hs + (size_t)i * HID + c);  // self-loop

    int j = beg;
    for (; j + 4 <= end; j += 4) {
        int s0 = col[j], s1 = col[j + 1], s2 = col[j + 2], s3 = col[j + 3];
        const float4 v0 = *(const float4*)(hs + (size_t)s0 * HID + c);
        const float4 v1 = *(const float4*)(hs + (size_t)s1 * HID + c);
        const float4 v2 = *(const float4*)(hs + (size_t)s2 * HID + c);
        const float4 v3 = *(const float4*)(hs + (size_t)s3 * HID + c);
        acc.x += (v0.x + v1.x) + (v2.x + v3.x);
        acc.y += (v0.y + v1.y) + (v2.y + v3.y);
        acc.z += (v0.z + v1.z) + (v2.z + v3.z);
        acc.w += (v0.w + v1.w) + (v2.w + v3.w);
    }
    for (; j < end; ++j) {
        int s = col[j];
        const float4 v = *(const float4*)(hs + (size_t)s * HID + c);
        acc.x += v.x; acc.y += v.y; acc.z += v.z; acc.w += v.w;
    }

    float di = dinv[i];
    float4 b = *(const float4*)(bias + c);
    float rx = fmaxf(acc.x * di + b.x, 0.0f);
    float ry = fmaxf(acc.y * di + b.y, 0.0f);
    float rz = fmaxf(acc.z * di + b.z, 0.0f);
    float rw = fmaxf(acc.w * di + b.w, 0.0f);
    ushort4 h, l;
    split2(rx, h.x, l.x);
    split2(ry, h.y, l.y);
    split2(rz, h.z, l.z);
    split2(rw, h.w, l.w);
    *(ushort4*)(Chi + (size_t)i * HID + c) = h;
    *(ushort4*)(Clo + (size_t)i * HID + c) = l;
}

// ---------------- split-bf16 MFMA GEMM: barrier-free register streaming ----------------
// C[N x M] = epilogue(A[N x K] @ W[K x M]); A = bf16 hi/lo planes [Npad][K],
// W = transposed bf16 hi/lo planes [M][K].
// NO LDS, NO __syncthreads. Both MFMA operands are loaded directly from global
// in fragment layout (A lane: row bm+tm*16+c16, 16 B at k0+quad*8 — 16 full
// cache lines per fragment load per wave). L1 serves cross-wave A reuse; L2
// serves cross-block B reuse (weights are L2-resident). Latency is hidden by
// TLP (no barrier to drain) — attacks the measured vmcnt(0)+s_barrier stall.
// Block: 4 waves, each computes 64 rows x 32 cols (TM=4, TN=2); block tile
// 64 x 128 (waves strided across columns).
// a*b ~= ah*bh + ah*bl + al*bh  (3 MFMA / 16x16 tile / 32-k chunk).
template <bool SCALE, bool BIAS, bool RELU, bool SPLIT>
__global__ __launch_bounds__(256, 4) void gemm3(
    const unsigned short* __restrict__ Ahi, const unsigned short* __restrict__ Alo,
    const unsigned short* __restrict__ Bhi, const unsigned short* __restrict__ Blo,
    const float* __restrict__ bias, const float* __restrict__ rowscale,
    float* __restrict__ outF, unsigned short* __restrict__ outHi,
    unsigned short* __restrict__ outLo, int Nout, int K, int M) {
    const int tid = threadIdx.x;
    const int wave = tid >> 6, lane = tid & 63;
    const int quad = lane >> 4, c16 = lane & 15;
    const int bm = blockIdx.y * 64;
    const int bn = blockIdx.x * 128 + wave * 32;

    float4v acc[4][2];
#pragma unroll
    for (int a = 0; a < 4; ++a)
#pragma unroll
        for (int b = 0; b < 2; ++b)
#pragma unroll
            for (int r = 0; r < 4; ++r) acc[a][b][r] = 0.0f;

    // per-lane element offsets (uniform kernel-arg base + VGPR offset)
    const size_t aoff = (size_t)(bm + c16) * K + quad * 8;
    const size_t boff = (size_t)(bn + c16) * K + quad * 8;
    const size_t rstep = (size_t)16 * K;  // 16 rows

    for (int k0 = 0; k0 < K; k0 += 32) {
        short8 afh[4], afl[4], bfh[2], bfl[2];
#pragma unroll
        for (int t = 0; t < 4; ++t) {
            afh[t] = *(const short8*)(Ahi + aoff + t * rstep + k0);
            afl[t] = *(const short8*)(Alo + aoff + t * rstep + k0);
        }
#pragma unroll
        for (int t = 0; t < 2; ++t) {
            bfh[t] = *(const short8*)(Bhi + boff + t * rstep + k0);
            bfl[t] = *(const short8*)(Blo + boff + t * rstep + k0);
        }
#pragma unroll
        for (int tm = 0; tm < 4; ++tm)
#pragma unroll
            for (int tn = 0; tn < 2; ++tn) {
                acc[tm][tn] = __builtin_amdgcn_mfma_f32_16x16x32_bf16(afh[tm], bfh[tn], acc[tm][tn], 0, 0, 0);
                acc[tm][tn] = __builtin_amdgcn_mfma_f32_16x16x32_bf16(afh[tm], bfl[tn], acc[tm][tn], 0, 0, 0);
                acc[tm][tn] = __builtin_amdgcn_mfma_f32_16x16x32_bf16(afl[tm], bfh[tn], acc[tm][tn], 0, 0, 0);
            }
    }

    // epilogue: C/D layout col=lane&15, row=quad*4+reg
#pragma unroll
    for (int tm = 0; tm < 4; ++tm) {
#pragma unroll
        for (int tn = 0; tn < 2; ++tn) {
            int colg = bn + tn * 16 + c16;
            float bv = BIAS ? bias[colg] : 0.0f;
#pragma unroll
            for (int r = 0; r < 4; ++r) {
                int row = bm + tm * 16 + quad * 4 + r;
                if (row >= Nout) continue;
                float v = acc[tm][tn][r];
                if (SCALE) v *= rowscale[row];
                if (BIAS) v += bv;
                if (RELU) v = fmaxf(v, 0.0f);
                if (SPLIT) {
                    unsigned short hi, lo;
                    split2(v, hi, lo);
                    outHi[(size_t)row * M + colg] = hi;
                    outLo[(size_t)row * M + colg] = lo;
                } else {
                    outF[(size_t)row * M + colg] = v;
                }
            }
        }
    }
}

// ---------------- host launch ----------------

extern "C" void kernel_launch(void* const* d_in, const int* in_sizes, int n_in,
                              void* d_out, int out_size, void* d_ws, size_t ws_size,
                              hipStream_t stream) {
    const float* x   = (const float*)d_in[0];
    const int*   ei  = (const int*)d_in[1];
    const float* Wg0 = (const float*)d_in[2];
    const float* bg0 = (const float*)d_in[3];
    const float* Wg1 = (const float*)d_in[4];
    const float* bg1 = (const float*)d_in[5];
    const float* Wg2 = (const float*)d_in[6];
    const float* bg2 = (const float*)d_in[7];
    const float* Wm0 = (const float*)d_in[8];
    const float* bm0 = (const float*)d_in[9];
    const float* Wm1 = (const float*)d_in[10];
    const float* bm1 = (const float*)d_in[11];
    float* out = (float*)d_out;

    const int N  = in_sizes[0] / HID;   // 50000
    const int E  = in_sizes[1] / 2;     // 800000
    const int M0 = in_sizes[9];         // 512
    const int M1 = in_sizes[11];        // 256
    const int Npad = ((N + 127) / 128) * 128;   // 50048
    const int nblk1024 = (N + 1023) / 1024;

    const int* src = ei;
    const int* dst = ei + E;

    char* ws = (char*)d_ws;
    size_t off = 0;
    auto alloc = [&](size_t bytes) {
        void* p = ws + off;
        off += (bytes + 255) & ~(size_t)255;
        return p;
    };
    int* degi   = (int*)alloc((size_t)N * 4);
    int* tmp    = (int*)alloc((size_t)N * 4);
    int* bsums  = (int*)alloc(4096);
    int* rowptr = (int*)alloc((size_t)(N + 1) * 4);
    int* cursor = (int*)alloc((size_t)N * 4);
    int* colbuf = (int*)alloc((size_t)E * 4);
    float* dinv = (float*)alloc((size_t)N * 4);
    unsigned short* WgT_hi[3];
    unsigned short* WgT_lo[3];
    for (int l = 0; l < 3; ++l) {
        WgT_hi[l] = (unsigned short*)alloc((size_t)HID * HID * 2);
        WgT_lo[l] = (unsigned short*)alloc((size_t)HID * HID * 2);
    }
    unsigned short* Wm0T_hi = (unsigned short*)alloc((size_t)M0 * HID * 2);
    unsigned short* Wm0T_lo = (unsigned short*)alloc((size_t)M0 * HID * 2);
    unsigned short* Wm1T_hi = (unsigned short*)alloc((size_t)M1 * M0 * 2);
    unsigned short* Wm1T_lo = (unsigned short*)alloc((size_t)M1 * M0 * 2);
    unsigned short* Chi = (unsigned short*)alloc((size_t)Npad * HID * 2);
    unsigned short* Clo = (unsigned short*)alloc((size_t)Npad * HID * 2);
    char* R = (char*)alloc((size_t)Npad * M0 * 2 * 2);  // overlay region
    unsigned short* Xhi = (unsigned short*)R;
    unsigned short* Xlo = (unsigned short*)(R + (size_t)Npad * HID * 2);
    float* A = (float*)(R + (size_t)Npad * HID * 4);    // hs fp32 [N][HID]
    unsigned short* Mhi = (unsigned short*)R;
    unsigned short* Mlo = (unsigned short*)(R + (size_t)Npad * M0 * 2);

    // ---- CSR build ----
    hipMemsetAsync(degi, 0, (size_t)N * 4, stream);
    deg_int_kernel<<<(E + 255) / 256, 256, 0, stream>>>(dst, degi, E);
    scan1_kernel<<<nblk1024, 1024, 0, stream>>>(degi, tmp, bsums, N);
    scan2_kernel<<<1, 1024, 0, stream>>>(bsums, nblk1024);
    scan3_kernel<<<(N + 255) / 256, 256, 0, stream>>>(tmp, degi, bsums, rowptr, cursor, dinv, N, E);
    fill_kernel<<<(E + 255) / 256, 256, 0, stream>>>(src, dst, cursor, colbuf, E);

    // ---- conversions ----
    xsplit_kernel<<<(N * HID / 4 + 255) / 256, 256, 0, stream>>>(x, Xhi, Xlo, N * HID / 4);
    {
        WSegs S;
        const float* Ws[5]      = {Wg0, Wg1, Wg2, Wm0, Wm1};
        unsigned short* His[5]  = {WgT_hi[0], WgT_hi[1], WgT_hi[2], Wm0T_hi, Wm1T_hi};
        unsigned short* Los[5]  = {WgT_lo[0], WgT_lo[1], WgT_lo[2], Wm0T_lo, Wm1T_lo};
        int Ks[5] = {HID, HID, HID, HID, M0};
        int Ms[5] = {HID, HID, HID, M0, M1};
        int start = 0;
        for (int s = 0; s < 5; ++s) {
            S.W[s] = Ws[s]; S.hi[s] = His[s]; S.lo[s] = Los[s];
            S.K[s] = Ks[s]; S.M[s] = Ms[s]; S.start[s] = start;
            start += Ks[s] * Ms[s];
        }
        wsplit_all_kernel<<<(start + 255) / 256, 256, 0, stream>>>(S, start);
    }

    // ---- 3 GCN layers ----
    const float* bg[3] = {bg0, bg1, bg2};
    const unsigned short* curHi = Xhi;
    const unsigned short* curLo = Xlo;
    long long gatherThreads = (long long)N * 32;
    for (int l = 0; l < 3; ++l) {
        gemm3<true, false, false, false><<<dim3(1, Npad / 64), 256, 0, stream>>>(
            curHi, curLo, WgT_hi[l], WgT_lo[l], nullptr, dinv, A, nullptr, nullptr, N, HID, HID);
        gather_kernel<<<(int)((gatherThreads + 255) / 256), 256, 0, stream>>>(
            A, rowptr, colbuf, dinv, bg[l], Chi, Clo, N);
        curHi = Chi;
        curLo = Clo;
    }

    // ---- MLP head ----
    gemm3<false, true, true, true><<<dim3(M0 / 128, Npad / 64), 256, 0, stream>>>(
        Chi, Clo, Wm0T_hi, Wm0T_lo, bm0, nullptr, nullptr, Mhi, Mlo, N, HID, M0);
    gemm3<false, true, true, false><<<dim3(M1 / 128, Npad / 64), 256, 0, stream>>>(
        Mhi, Mlo, Wm1T_hi, Wm1T_lo, bm1, nullptr, out, nullptr, nullptr, N, M0, M1);
}

// Round 8
// 653.762 us; speedup vs baseline: 1.1041x; 1.1041x over previous
//
#include <hip/hip_runtime.h>

#define HID 128

using short8  = __attribute__((ext_vector_type(8))) short;
using float4v = __attribute__((ext_vector_type(4))) float;

// ---- fp32 -> bf16 (RNE) helpers ----
__device__ __forceinline__ unsigned short f2bf(float f) {
    unsigned u = __float_as_uint(f);
    u = u + 0x7fff + ((u >> 16) & 1);
    return (unsigned short)(u >> 16);
}
__device__ __forceinline__ float bf2f(unsigned short h) {
    return __uint_as_float(((unsigned)h) << 16);
}
__device__ __forceinline__ void split2(float x, unsigned short& hi, unsigned short& lo) {
    hi = f2bf(x);
    lo = f2bf(x - bf2f(hi));
}

// ---- async global->LDS, 16 B per lane (wave-uniform base + lane*16) ----
typedef const __attribute__((address_space(1))) unsigned int* gas_ptr;
typedef __attribute__((address_space(3))) unsigned int* las_ptr;
__device__ __forceinline__ void gld16(const unsigned short* g, unsigned short* l) {
    __builtin_amdgcn_global_load_lds((gas_ptr)g, (las_ptr)l, 16, 0, 0);
}

// ---------------- CSR build ----------------

__global__ void deg_int_kernel(const int* __restrict__ dst, int* __restrict__ degi, int E) {
    int i = blockIdx.x * blockDim.x + threadIdx.x;
    if (i < E) atomicAdd(&degi[dst[i]], 1);
}

__global__ __launch_bounds__(1024) void scan1_kernel(
    const int* __restrict__ in, int* __restrict__ incl, int* __restrict__ bsums, int N) {
    __shared__ int sm[1024];
    int i = blockIdx.x * 1024 + threadIdx.x;
    int v = (i < N) ? in[i] : 0;
    sm[threadIdx.x] = v;
    __syncthreads();
    for (int off = 1; off < 1024; off <<= 1) {
        int t = (threadIdx.x >= (unsigned)off) ? sm[threadIdx.x - off] : 0;
        __syncthreads();
        sm[threadIdx.x] += t;
        __syncthreads();
    }
    if (i < N) incl[i] = sm[threadIdx.x];
    if (threadIdx.x == 1023) bsums[blockIdx.x] = sm[1023];
}

__global__ __launch_bounds__(1024) void scan2_kernel(int* __restrict__ bsums, int nblk) {
    __shared__ int sm[1024];
    int t = threadIdx.x;
    int v = (t < nblk) ? bsums[t] : 0;
    sm[t] = v;
    __syncthreads();
    for (int off = 1; off < 1024; off <<= 1) {
        int u = (t >= (unsigned)off) ? sm[t - off] : 0;
        __syncthreads();
        sm[t] += u;
        __syncthreads();
    }
    if (t < nblk) bsums[t] = sm[t] - v;  // exclusive
}

__global__ void scan3_kernel(const int* __restrict__ incl, const int* __restrict__ degi,
                             const int* __restrict__ bsums, int* __restrict__ rowptr,
                             int* __restrict__ cursor, float* __restrict__ dinv, int N, int E) {
    int i = blockIdx.x * blockDim.x + threadIdx.x;
    if (i < N) {
        int r = bsums[i >> 10] + incl[i] - degi[i];
        rowptr[i] = r;
        cursor[i] = r;
        dinv[i] = rsqrtf((float)degi[i] + 1.0f);
    }
    if (i == 0) rowptr[N] = E;
}

__global__ void fill_kernel(const int* __restrict__ src, const int* __restrict__ dst,
                            int* __restrict__ cursor, int* __restrict__ col, int E) {
    int e = blockIdx.x * blockDim.x + threadIdx.x;
    if (e < E) {
        int d = dst[e];
        int pos = atomicAdd(&cursor[d], 1);
        col[pos] = src[e];
    }
}

// ---------------- input / weight conversion ----------------

__global__ void xsplit_kernel(const float* __restrict__ x, unsigned short* __restrict__ Xhi,
                              unsigned short* __restrict__ Xlo, int total4) {
    int i = blockIdx.x * blockDim.x + threadIdx.x;
    if (i >= total4) return;
    const float4 v = *(const float4*)(x + (size_t)i * 4);
    ushort4 h, l;
    split2(v.x, h.x, l.x);
    split2(v.y, h.y, l.y);
    split2(v.z, h.z, l.z);
    split2(v.w, h.w, l.w);
    *(ushort4*)(Xhi + (size_t)i * 4) = h;
    *(ushort4*)(Xlo + (size_t)i * 4) = l;
}

// all 5 weight matrices transposed+split in one dispatch
struct WSegs {
    const float* W[5];
    unsigned short* hi[5];
    unsigned short* lo[5];
    int K[5], M[5], start[5];
};

__global__ void wsplit_all_kernel(WSegs S, int total) {
    int idx = blockIdx.x * blockDim.x + threadIdx.x;
    if (idx >= total) return;
    int s = 0;
#pragma unroll
    for (int t = 1; t < 5; ++t)
        if (idx >= S.start[t]) s = t;
    int local = idx - S.start[s];
    int M = S.M[s], K = S.K[s];
    int k = local / M;
    int m = local - k * M;
    unsigned short hi, lo;
    split2(S.W[s][local], hi, lo);
    S.hi[s][(size_t)m * K + k] = hi;
    S.lo[s][(size_t)m * K + k] = lo;
}

// ---------------- feature-chunked gather-reduce + finalize -> split planes ----------------
// grid.z = 8 feature chunks of 16 floats. Per chunk the gathered array slice is
// 50000 x 64 B = 3.2 MB < 4 MiB XCD-L2, so the random neighbor reads hit L2
// instead of LLC. 4 lanes per node, one float4 (16 B) each -> each neighbor
// access is one 64 B cache line per 4-lane group.
__global__ __launch_bounds__(256) void gather_chunk_kernel(
    const float* __restrict__ hs, const int* __restrict__ rowptr,
    const int* __restrict__ col, const float* __restrict__ dinv,
    const float* __restrict__ bias, unsigned short* __restrict__ Chi,
    unsigned short* __restrict__ Clo, int N) {
    int node = blockIdx.x * 64 + ((int)threadIdx.x >> 2);
    if (node >= N) return;
    int fo = (int)blockIdx.z * 16 + ((int)threadIdx.x & 3) * 4;  // feature offset

    int beg = rowptr[node];
    int end = rowptr[node + 1];

    const float* base = hs + fo;
    float4 acc = *(const float4*)(base + (size_t)node * HID);  // self-loop term

    int j = beg;
    for (; j + 4 <= end; j += 4) {
        int s0 = col[j], s1 = col[j + 1], s2 = col[j + 2], s3 = col[j + 3];
        const float4 v0 = *(const float4*)(base + (size_t)s0 * HID);
        const float4 v1 = *(const float4*)(base + (size_t)s1 * HID);
        const float4 v2 = *(const float4*)(base + (size_t)s2 * HID);
        const float4 v3 = *(const float4*)(base + (size_t)s3 * HID);
        acc.x += (v0.x + v1.x) + (v2.x + v3.x);
        acc.y += (v0.y + v1.y) + (v2.y + v3.y);
        acc.z += (v0.z + v1.z) + (v2.z + v3.z);
        acc.w += (v0.w + v1.w) + (v2.w + v3.w);
    }
    for (; j < end; ++j) {
        int s = col[j];
        const float4 v = *(const float4*)(base + (size_t)s * HID);
        acc.x += v.x; acc.y += v.y; acc.z += v.z; acc.w += v.w;
    }

    float di = dinv[node];
    float4 b = *(const float4*)(bias + fo);
    float rx = fmaxf(acc.x * di + b.x, 0.0f);
    float ry = fmaxf(acc.y * di + b.y, 0.0f);
    float rz = fmaxf(acc.z * di + b.z, 0.0f);
    float rw = fmaxf(acc.w * di + b.w, 0.0f);
    ushort4 h, l;
    split2(rx, h.x, l.x);
    split2(ry, h.y, l.y);
    split2(rz, h.z, l.z);
    split2(rw, h.w, l.w);
    *(ushort4*)(Chi + (size_t)node * HID + fo) = h;
    *(ushort4*)(Clo + (size_t)node * HID + fo) = l;
}

// ---------------- split-bf16 MFMA GEMM: single-barrier double-buffered K-loop ----------------
// (R6 structure — best measured GEMM: MLP1 67 us.)
// C[N x M] = epilogue(A[N x K] @ W[K x M]); A = bf16 hi/lo planes [Npad][K],
// W = transposed bf16 hi/lo planes [M][K].
// BM=64, BN=128, BK=32. 4 waves, each 64x32 (TM=4, TN=2).
// a*b ~= ah*bh + ah*bl + al*bh  (3 MFMA / tile / 32-k chunk).
template <bool SCALE, bool BIAS, bool RELU, bool SPLIT>
__global__ __launch_bounds__(256, 3) void gemm2(
    const unsigned short* __restrict__ Ahi, const unsigned short* __restrict__ Alo,
    const unsigned short* __restrict__ Bhi, const unsigned short* __restrict__ Blo,
    const float* __restrict__ bias, const float* __restrict__ rowscale,
    float* __restrict__ outF, unsigned short* __restrict__ outHi,
    unsigned short* __restrict__ outLo, int Nout, int K, int M) {
    __shared__ unsigned short lds[2 * 12288];  // 48 KB

    const int tid = threadIdx.x;
    const int bm = blockIdx.y * 64;
    const int bn = blockIdx.x * 128;
    const int wave = tid >> 6, lane = tid & 63;
    const int quad = lane >> 4, c16 = lane & 15;
    const int wn = wave * 32;

    float4v acc[4][2];
#pragma unroll
    for (int a = 0; a < 4; ++a)
#pragma unroll
        for (int b = 0; b < 2; ++b)
#pragma unroll
            for (int r = 0; r < 4; ++r) acc[a][b][r] = 0.0f;

    const int r0 = tid >> 2;            // 0..63
    const int kq0 = (tid & 3) * 8;      // 0,8,16,24

    const unsigned short* gAh = Ahi + (size_t)(bm + r0) * K + kq0;
    const unsigned short* gAl = Alo + (size_t)(bm + r0) * K + kq0;
    const unsigned short* gBh0 = Bhi + (size_t)(bn + r0) * K + kq0;
    const unsigned short* gBh1 = Bhi + (size_t)(bn + r0 + 64) * K + kq0;
    const unsigned short* gBl0 = Blo + (size_t)(bn + r0) * K + kq0;
    const unsigned short* gBl1 = Blo + (size_t)(bn + r0 + 64) * K + kq0;

    auto issue = [&](int c) {
        unsigned short* buf = lds + (size_t)(c & 1) * 12288;
        int k0 = c * 32;
        gld16(gAh + k0, buf + (size_t)tid * 8);
        gld16(gAl + k0, buf + 2048 + (size_t)tid * 8);
        gld16(gBh0 + k0, buf + 4096 + (size_t)tid * 8);
        gld16(gBh1 + k0, buf + 4096 + (size_t)(tid + 256) * 8);
        gld16(gBl0 + k0, buf + 8192 + (size_t)tid * 8);
        gld16(gBl1 + k0, buf + 8192 + (size_t)(tid + 256) * 8);
    };

    issue(0);
    __syncthreads();

    const int nch = K >> 5;
    for (int c = 0; c < nch; ++c) {
        if (c + 1 < nch) issue(c + 1);  // DMA next chunk into other buffer

        const unsigned short* buf = lds + (size_t)(c & 1) * 12288;
        short8 afh[4], afl[4], bfh[2], bfl[2];
#pragma unroll
        for (int t = 0; t < 4; ++t) {
            int am = t * 16 + c16;
            afh[t] = *(const short8*)&buf[am * 32 + quad * 8];
            afl[t] = *(const short8*)&buf[2048 + am * 32 + quad * 8];
        }
#pragma unroll
        for (int t = 0; t < 2; ++t) {
            int bn_ = wn + t * 16 + c16;
            bfh[t] = *(const short8*)&buf[4096 + bn_ * 32 + quad * 8];
            bfl[t] = *(const short8*)&buf[8192 + bn_ * 32 + quad * 8];
        }
#pragma unroll
        for (int tm = 0; tm < 4; ++tm)
#pragma unroll
            for (int tn = 0; tn < 2; ++tn) {
                acc[tm][tn] = __builtin_amdgcn_mfma_f32_16x16x32_bf16(afh[tm], bfh[tn], acc[tm][tn], 0, 0, 0);
                acc[tm][tn] = __builtin_amdgcn_mfma_f32_16x16x32_bf16(afh[tm], bfl[tn], acc[tm][tn], 0, 0, 0);
                acc[tm][tn] = __builtin_amdgcn_mfma_f32_16x16x32_bf16(afl[tm], bfh[tn], acc[tm][tn], 0, 0, 0);
            }
        __syncthreads();
    }

    // epilogue: C/D layout col=lane&15, row=quad*4+reg
#pragma unroll
    for (int tm = 0; tm < 4; ++tm) {
#pragma unroll
        for (int tn = 0; tn < 2; ++tn) {
            int colg = bn + wn + tn * 16 + c16;
            float bv = BIAS ? bias[colg] : 0.0f;
#pragma unroll
            for (int r = 0; r < 4; ++r) {
                int row = bm + tm * 16 + quad * 4 + r;
                if (row >= Nout) continue;
                float v = acc[tm][tn][r];
                if (SCALE) v *= rowscale[row];
                if (BIAS) v += bv;
                if (RELU) v = fmaxf(v, 0.0f);
                if (SPLIT) {
                    unsigned short hi, lo;
                    split2(v, hi, lo);
                    outHi[(size_t)row * M + colg] = hi;
                    outLo[(size_t)row * M + colg] = lo;
                } else {
                    outF[(size_t)row * M + colg] = v;
                }
            }
        }
    }
}

// ---------------- host launch ----------------

extern "C" void kernel_launch(void* const* d_in, const int* in_sizes, int n_in,
                              void* d_out, int out_size, void* d_ws, size_t ws_size,
                              hipStream_t stream) {
    const float* x   = (const float*)d_in[0];
    const int*   ei  = (const int*)d_in[1];
    const float* Wg0 = (const float*)d_in[2];
    const float* bg0 = (const float*)d_in[3];
    const float* Wg1 = (const float*)d_in[4];
    const float* bg1 = (const float*)d_in[5];
    const float* Wg2 = (const float*)d_in[6];
    const float* bg2 = (const float*)d_in[7];
    const float* Wm0 = (const float*)d_in[8];
    const float* bm0 = (const float*)d_in[9];
    const float* Wm1 = (const float*)d_in[10];
    const float* bm1 = (const float*)d_in[11];
    float* out = (float*)d_out;

    const int N  = in_sizes[0] / HID;   // 50000
    const int E  = in_sizes[1] / 2;     // 800000
    const int M0 = in_sizes[9];         // 512
    const int M1 = in_sizes[11];        // 256
    const int Npad = ((N + 127) / 128) * 128;   // 50048
    const int nblk1024 = (N + 1023) / 1024;

    const int* src = ei;
    const int* dst = ei + E;

    char* ws = (char*)d_ws;
    size_t off = 0;
    auto alloc = [&](size_t bytes) {
        void* p = ws + off;
        off += (bytes + 255) & ~(size_t)255;
        return p;
    };
    int* degi   = (int*)alloc((size_t)N * 4);
    int* tmp    = (int*)alloc((size_t)N * 4);
    int* bsums  = (int*)alloc(4096);
    int* rowptr = (int*)alloc((size_t)(N + 1) * 4);
    int* cursor = (int*)alloc((size_t)N * 4);
    int* colbuf = (int*)alloc((size_t)E * 4);
    float* dinv = (float*)alloc((size_t)N * 4);
    unsigned short* WgT_hi[3];
    unsigned short* WgT_lo[3];
    for (int l = 0; l < 3; ++l) {
        WgT_hi[l] = (unsigned short*)alloc((size_t)HID * HID * 2);
        WgT_lo[l] = (unsigned short*)alloc((size_t)HID * HID * 2);
    }
    unsigned short* Wm0T_hi = (unsigned short*)alloc((size_t)M0 * HID * 2);
    unsigned short* Wm0T_lo = (unsigned short*)alloc((size_t)M0 * HID * 2);
    unsigned short* Wm1T_hi = (unsigned short*)alloc((size_t)M1 * M0 * 2);
    unsigned short* Wm1T_lo = (unsigned short*)alloc((size_t)M1 * M0 * 2);
    unsigned short* Chi = (unsigned short*)alloc((size_t)Npad * HID * 2);
    unsigned short* Clo = (unsigned short*)alloc((size_t)Npad * HID * 2);
    char* R = (char*)alloc((size_t)Npad * M0 * 2 * 2);  // overlay region
    unsigned short* Xhi = (unsigned short*)R;
    unsigned short* Xlo = (unsigned short*)(R + (size_t)Npad * HID * 2);
    float* A = (float*)(R + (size_t)Npad * HID * 4);    // hs fp32 [N][HID]
    unsigned short* Mhi = (unsigned short*)R;
    unsigned short* Mlo = (unsigned short*)(R + (size_t)Npad * M0 * 2);

    // ---- CSR build ----
    hipMemsetAsync(degi, 0, (size_t)N * 4, stream);
    deg_int_kernel<<<(E + 255) / 256, 256, 0, stream>>>(dst, degi, E);
    scan1_kernel<<<nblk1024, 1024, 0, stream>>>(degi, tmp, bsums, N);
    scan2_kernel<<<1, 1024, 0, stream>>>(bsums, nblk1024);
    scan3_kernel<<<(N + 255) / 256, 256, 0, stream>>>(tmp, degi, bsums, rowptr, cursor, dinv, N, E);
    fill_kernel<<<(E + 255) / 256, 256, 0, stream>>>(src, dst, cursor, colbuf, E);

    // ---- conversions ----
    xsplit_kernel<<<(N * HID / 4 + 255) / 256, 256, 0, stream>>>(x, Xhi, Xlo, N * HID / 4);
    {
        WSegs S;
        const float* Ws[5]      = {Wg0, Wg1, Wg2, Wm0, Wm1};
        unsigned short* His[5]  = {WgT_hi[0], WgT_hi[1], WgT_hi[2], Wm0T_hi, Wm1T_hi};
        unsigned short* Los[5]  = {WgT_lo[0], WgT_lo[1], WgT_lo[2], Wm0T_lo, Wm1T_lo};
        int Ks[5] = {HID, HID, HID, HID, M0};
        int Ms[5] = {HID, HID, HID, M0, M1};
        int start = 0;
        for (int s = 0; s < 5; ++s) {
            S.W[s] = Ws[s]; S.hi[s] = His[s]; S.lo[s] = Los[s];
            S.K[s] = Ks[s]; S.M[s] = Ms[s]; S.start[s] = start;
            start += Ks[s] * Ms[s];
        }
        wsplit_all_kernel<<<(start + 255) / 256, 256, 0, stream>>>(S, start);
    }

    // ---- 3 GCN layers ----
    const float* bg[3] = {bg0, bg1, bg2};
    const unsigned short* curHi = Xhi;
    const unsigned short* curLo = Xlo;
    dim3 ggrid((N + 63) / 64, 1, 8);
    for (int l = 0; l < 3; ++l) {
        gemm2<true, false, false, false><<<dim3(1, Npad / 64), 256, 0, stream>>>(
            curHi, curLo, WgT_hi[l], WgT_lo[l], nullptr, dinv, A, nullptr, nullptr, N, HID, HID);
        gather_chunk_kernel<<<ggrid, 256, 0, stream>>>(
            A, rowptr, colbuf, dinv, bg[l], Chi, Clo, N);
        curHi = Chi;
        curLo = Clo;
    }

    // ---- MLP head ----
    gemm2<false, true, true, true><<<dim3(M0 / 128, Npad / 64), 256, 0, stream>>>(
        Chi, Clo, Wm0T_hi, Wm0T_lo, bm0, nullptr, nullptr, Mhi, Mlo, N, HID, M0);
    gemm2<false, true, true, false><<<dim3(M1 / 128, Npad / 64), 256, 0, stream>>>(
        Mhi, Mlo, Wm1T_hi, Wm1T_lo, bm1, nullptr, out, nullptr, nullptr, N, M0, M1);
}

// Round 9
// 397.999 us; speedup vs baseline: 1.8135x; 1.6426x over previous
//
#include <hip/hip_runtime.h>

#define HID 128

typedef _Float16 half8 __attribute__((ext_vector_type(8)));
typedef _Float16 half4h __attribute__((ext_vector_type(4)));
using float4v = __attribute__((ext_vector_type(4))) float;

// ---- async global->LDS, 16 B per lane (wave-uniform base + lane*16) ----
typedef const __attribute__((address_space(1))) unsigned int* gas_ptr;
typedef __attribute__((address_space(3))) unsigned int* las_ptr;
__device__ __forceinline__ void gld16(const void* g, void* l) {
    __builtin_amdgcn_global_load_lds((gas_ptr)g, (las_ptr)l, 16, 0, 0);
}

// ---------------- CSR build ----------------

__global__ void deg_int_kernel(const int* __restrict__ dst, int* __restrict__ degi, int E) {
    int i = blockIdx.x * blockDim.x + threadIdx.x;
    if (i < E) atomicAdd(&degi[dst[i]], 1);
}

__global__ __launch_bounds__(1024) void scan1_kernel(
    const int* __restrict__ in, int* __restrict__ incl, int* __restrict__ bsums, int N) {
    __shared__ int sm[1024];
    int i = blockIdx.x * 1024 + threadIdx.x;
    int v = (i < N) ? in[i] : 0;
    sm[threadIdx.x] = v;
    __syncthreads();
    for (int off = 1; off < 1024; off <<= 1) {
        int t = (threadIdx.x >= (unsigned)off) ? sm[threadIdx.x - off] : 0;
        __syncthreads();
        sm[threadIdx.x] += t;
        __syncthreads();
    }
    if (i < N) incl[i] = sm[threadIdx.x];
    if (threadIdx.x == 1023) bsums[blockIdx.x] = sm[1023];
}

__global__ __launch_bounds__(1024) void scan2_kernel(int* __restrict__ bsums, int nblk) {
    __shared__ int sm[1024];
    int t = threadIdx.x;
    int v = (t < nblk) ? bsums[t] : 0;
    sm[t] = v;
    __syncthreads();
    for (int off = 1; off < 1024; off <<= 1) {
        int u = (t >= (unsigned)off) ? sm[t - off] : 0;
        __syncthreads();
        sm[t] += u;
        __syncthreads();
    }
    if (t < nblk) bsums[t] = sm[t] - v;  // exclusive
}

__global__ void scan3_kernel(const int* __restrict__ incl, const int* __restrict__ degi,
                             const int* __restrict__ bsums, int* __restrict__ rowptr,
                             int* __restrict__ cursor, float* __restrict__ dinv, int N, int E) {
    int i = blockIdx.x * blockDim.x + threadIdx.x;
    if (i < N) {
        int r = bsums[i >> 10] + incl[i] - degi[i];
        rowptr[i] = r;
        cursor[i] = r;
        dinv[i] = rsqrtf((float)degi[i] + 1.0f);
    }
    if (i == 0) rowptr[N] = E;
}

__global__ void fill_kernel(const int* __restrict__ src, const int* __restrict__ dst,
                            int* __restrict__ cursor, int* __restrict__ col, int E) {
    int e = blockIdx.x * blockDim.x + threadIdx.x;
    if (e < E) {
        int d = dst[e];
        int pos = atomicAdd(&cursor[d], 1);
        col[pos] = src[e];
    }
}

// ---------------- conversions ----------------

__global__ void xconv_kernel(const float* __restrict__ x, _Float16* __restrict__ Xh, int total4) {
    int i = blockIdx.x * blockDim.x + threadIdx.x;
    if (i >= total4) return;
    const float4 v = *(const float4*)(x + (size_t)i * 4);
    half4h h;
    h.x = (_Float16)v.x; h.y = (_Float16)v.y; h.z = (_Float16)v.z; h.w = (_Float16)v.w;
    *(half4h*)(Xh + (size_t)i * 4) = h;
}

// all 5 weight matrices transposed+converted in one dispatch: Wh[m*K+k] = W[k*M+m]
struct WSegs {
    const float* W[5];
    _Float16* H[5];
    int K[5], M[5], start[5];
};

__global__ void wconv_all_kernel(WSegs S, int total) {
    int idx = blockIdx.x * blockDim.x + threadIdx.x;
    if (idx >= total) return;
    int s = 0;
#pragma unroll
    for (int t = 1; t < 5; ++t)
        if (idx >= S.start[t]) s = t;
    int local = idx - S.start[s];
    int M = S.M[s], K = S.K[s];
    int k = local / M;
    int m = local - k * M;
    S.H[s][(size_t)m * K + k] = (_Float16)S.W[s][local];
}

// ---------------- fused gather-reduce + finalize (fp16 in/out, fp32 accumulate) ----------------
// out[i] = relu((sum_nbr hs[col[j]] + hs[i]) * dinv[i] + b), hs already scaled by dinv[src].
// 32 lanes per node, 4 halves (8 B) per lane; one 256 B row per neighbor per half-wave.
__global__ __launch_bounds__(256) void gather_kernel(
    const _Float16* __restrict__ hs, const int* __restrict__ rowptr,
    const int* __restrict__ col, const float* __restrict__ dinv,
    const float* __restrict__ bias, _Float16* __restrict__ Ch, int N) {
    long long idx = (long long)blockIdx.x * blockDim.x + threadIdx.x;
    int i = (int)(idx >> 5);
    if (i >= N) return;
    int c = ((int)idx & 31) * 4;

    int beg = rowptr[i];
    int end = rowptr[i + 1];

    const half4h sv = *(const half4h*)(hs + (size_t)i * HID + c);  // self-loop
    float ax = (float)sv.x, ay = (float)sv.y, az = (float)sv.z, aw = (float)sv.w;

    int j = beg;
    for (; j + 4 <= end; j += 4) {
        int s0 = col[j], s1 = col[j + 1], s2 = col[j + 2], s3 = col[j + 3];
        const half4h v0 = *(const half4h*)(hs + (size_t)s0 * HID + c);
        const half4h v1 = *(const half4h*)(hs + (size_t)s1 * HID + c);
        const half4h v2 = *(const half4h*)(hs + (size_t)s2 * HID + c);
        const half4h v3 = *(const half4h*)(hs + (size_t)s3 * HID + c);
        ax += (float)v0.x + (float)v1.x + (float)v2.x + (float)v3.x;
        ay += (float)v0.y + (float)v1.y + (float)v2.y + (float)v3.y;
        az += (float)v0.z + (float)v1.z + (float)v2.z + (float)v3.z;
        aw += (float)v0.w + (float)v1.w + (float)v2.w + (float)v3.w;
    }
    for (; j < end; ++j) {
        int s = col[j];
        const half4h v = *(const half4h*)(hs + (size_t)s * HID + c);
        ax += (float)v.x; ay += (float)v.y; az += (float)v.z; aw += (float)v.w;
    }

    float di = dinv[i];
    float4 b = *(const float4*)(bias + c);
    half4h r;
    r.x = (_Float16)fmaxf(ax * di + b.x, 0.0f);
    r.y = (_Float16)fmaxf(ay * di + b.y, 0.0f);
    r.z = (_Float16)fmaxf(az * di + b.z, 0.0f);
    r.w = (_Float16)fmaxf(aw * di + b.w, 0.0f);
    *(half4h*)(Ch + (size_t)i * HID + c) = r;
}

// ---------------- fp16 MFMA GEMM: single-barrier double-buffered K-loop ----------------
// C[N x M] = epilogue(A[N x K] @ W[K x M]); A = fp16 [Npad][K], W = fp16 transposed [M][K].
// BM=64, BN=128, BK=32. 4 waves, each 64x32 (TM=4, TN=2). fp32 accumulate.
// Per-buffer LDS (halves): A[64*32]=2048, B[128*32]=4096 -> 6144 (12 KB); dbuf 24 KB.
template <bool SCALE, bool BIAS, bool RELU, bool OUTHALF>
__global__ __launch_bounds__(256, 4) void gemm2h(
    const _Float16* __restrict__ Ah, const _Float16* __restrict__ Bh,
    const float* __restrict__ bias, const float* __restrict__ rowscale,
    float* __restrict__ outF, _Float16* __restrict__ outH, int Nout, int K, int M) {
    __shared__ _Float16 lds[2 * 6144];  // 24 KB

    const int tid = threadIdx.x;
    const int bm = blockIdx.y * 64;
    const int bn = blockIdx.x * 128;
    const int wave = tid >> 6, lane = tid & 63;
    const int quad = lane >> 4, c16 = lane & 15;
    const int wn = wave * 32;

    float4v acc[4][2];
#pragma unroll
    for (int a = 0; a < 4; ++a)
#pragma unroll
        for (int b = 0; b < 2; ++b)
#pragma unroll
            for (int r = 0; r < 4; ++r) acc[a][b][r] = 0.0f;

    const int r0 = tid >> 2;            // 0..63
    const int kq0 = (tid & 3) * 8;      // 0,8,16,24 (halves)

    const _Float16* gA  = Ah + (size_t)(bm + r0) * K + kq0;
    const _Float16* gB0 = Bh + (size_t)(bn + r0) * K + kq0;
    const _Float16* gB1 = Bh + (size_t)(bn + r0 + 64) * K + kq0;

    auto issue = [&](int c) {
        _Float16* buf = lds + (size_t)(c & 1) * 6144;
        int k0 = c * 32;
        gld16(gA + k0, buf + (size_t)tid * 8);
        gld16(gB0 + k0, buf + 2048 + (size_t)tid * 8);
        gld16(gB1 + k0, buf + 2048 + (size_t)(tid + 256) * 8);
    };

    issue(0);
    __syncthreads();

    const int nch = K >> 5;
    for (int c = 0; c < nch; ++c) {
        if (c + 1 < nch) issue(c + 1);  // DMA next chunk into other buffer

        const _Float16* buf = lds + (size_t)(c & 1) * 6144;
        half8 af[4], bf[2];
#pragma unroll
        for (int t = 0; t < 4; ++t)
            af[t] = *(const half8*)&buf[(t * 16 + c16) * 32 + quad * 8];
#pragma unroll
        for (int t = 0; t < 2; ++t)
            bf[t] = *(const half8*)&buf[2048 + (wn + t * 16 + c16) * 32 + quad * 8];
#pragma unroll
        for (int tm = 0; tm < 4; ++tm)
#pragma unroll
            for (int tn = 0; tn < 2; ++tn)
                acc[tm][tn] = __builtin_amdgcn_mfma_f32_16x16x32_f16(af[tm], bf[tn], acc[tm][tn], 0, 0, 0);
        __syncthreads();
    }

    // epilogue: C/D layout col=lane&15, row=quad*4+reg
#pragma unroll
    for (int tm = 0; tm < 4; ++tm) {
#pragma unroll
        for (int tn = 0; tn < 2; ++tn) {
            int colg = bn + wn + tn * 16 + c16;
            float bv = BIAS ? bias[colg] : 0.0f;
#pragma unroll
            for (int r = 0; r < 4; ++r) {
                int row = bm + tm * 16 + quad * 4 + r;
                if (row >= Nout) continue;
                float v = acc[tm][tn][r];
                if (SCALE) v *= rowscale[row];
                if (BIAS) v += bv;
                if (RELU) v = fmaxf(v, 0.0f);
                if (OUTHALF) outH[(size_t)row * M + colg] = (_Float16)v;
                else         outF[(size_t)row * M + colg] = v;
            }
        }
    }
}

// ---------------- host launch ----------------

extern "C" void kernel_launch(void* const* d_in, const int* in_sizes, int n_in,
                              void* d_out, int out_size, void* d_ws, size_t ws_size,
                              hipStream_t stream) {
    const float* x   = (const float*)d_in[0];
    const int*   ei  = (const int*)d_in[1];
    const float* Wg0 = (const float*)d_in[2];
    const float* bg0 = (const float*)d_in[3];
    const float* Wg1 = (const float*)d_in[4];
    const float* bg1 = (const float*)d_in[5];
    const float* Wg2 = (const float*)d_in[6];
    const float* bg2 = (const float*)d_in[7];
    const float* Wm0 = (const float*)d_in[8];
    const float* bm0 = (const float*)d_in[9];
    const float* Wm1 = (const float*)d_in[10];
    const float* bm1 = (const float*)d_in[11];
    float* out = (float*)d_out;

    const int N  = in_sizes[0] / HID;   // 50000
    const int E  = in_sizes[1] / 2;     // 800000
    const int M0 = in_sizes[9];         // 512
    const int M1 = in_sizes[11];        // 256
    const int Npad = ((N + 127) / 128) * 128;   // 50048
    const int nblk1024 = (N + 1023) / 1024;

    const int* src = ei;
    const int* dst = ei + E;

    char* ws = (char*)d_ws;
    size_t off = 0;
    auto alloc = [&](size_t bytes) {
        void* p = ws + off;
        off += (bytes + 255) & ~(size_t)255;
        return p;
    };
    int* degi   = (int*)alloc((size_t)N * 4);
    int* tmp    = (int*)alloc((size_t)N * 4);
    int* bsums  = (int*)alloc(4096);
    int* rowptr = (int*)alloc((size_t)(N + 1) * 4);
    int* cursor = (int*)alloc((size_t)N * 4);
    int* colbuf = (int*)alloc((size_t)E * 4);
    float* dinv = (float*)alloc((size_t)N * 4);
    _Float16* WgT[3];
    for (int l = 0; l < 3; ++l)
        WgT[l] = (_Float16*)alloc((size_t)HID * HID * 2);
    _Float16* Wm0T = (_Float16*)alloc((size_t)M0 * HID * 2);
    _Float16* Wm1T = (_Float16*)alloc((size_t)M1 * M0 * 2);
    _Float16* Xh = (_Float16*)alloc((size_t)Npad * HID * 2);   // fp16 input plane
    _Float16* Hs = (_Float16*)alloc((size_t)Npad * HID * 2);   // GEMM out / gather in
    _Float16* Ch = (_Float16*)alloc((size_t)Npad * HID * 2);   // gather out
    _Float16* Mh = (_Float16*)alloc((size_t)Npad * M0 * 2);    // MLP hidden

    // ---- CSR build ----
    hipMemsetAsync(degi, 0, (size_t)N * 4, stream);
    deg_int_kernel<<<(E + 255) / 256, 256, 0, stream>>>(dst, degi, E);
    scan1_kernel<<<nblk1024, 1024, 0, stream>>>(degi, tmp, bsums, N);
    scan2_kernel<<<1, 1024, 0, stream>>>(bsums, nblk1024);
    scan3_kernel<<<(N + 255) / 256, 256, 0, stream>>>(tmp, degi, bsums, rowptr, cursor, dinv, N, E);
    fill_kernel<<<(E + 255) / 256, 256, 0, stream>>>(src, dst, cursor, colbuf, E);

    // ---- conversions ----
    xconv_kernel<<<(N * HID / 4 + 255) / 256, 256, 0, stream>>>(x, Xh, N * HID / 4);
    {
        WSegs S;
        const float* Ws[5] = {Wg0, Wg1, Wg2, Wm0, Wm1};
        _Float16* Hs5[5]   = {WgT[0], WgT[1], WgT[2], Wm0T, Wm1T};
        int Ks[5] = {HID, HID, HID, HID, M0};
        int Ms[5] = {HID, HID, HID, M0, M1};
        int start = 0;
        for (int s = 0; s < 5; ++s) {
            S.W[s] = Ws[s]; S.H[s] = Hs5[s];
            S.K[s] = Ks[s]; S.M[s] = Ms[s]; S.start[s] = start;
            start += Ks[s] * Ms[s];
        }
        wconv_all_kernel<<<(start + 255) / 256, 256, 0, stream>>>(S, start);
    }

    // ---- 3 GCN layers ----
    const float* bg[3] = {bg0, bg1, bg2};
    const _Float16* cur = Xh;
    long long gatherThreads = (long long)N * 32;
    for (int l = 0; l < 3; ++l) {
        gemm2h<true, false, false, true><<<dim3(1, Npad / 64), 256, 0, stream>>>(
            cur, WgT[l], nullptr, dinv, nullptr, Hs, N, HID, HID);
        gather_kernel<<<(int)((gatherThreads + 255) / 256), 256, 0, stream>>>(
            Hs, rowptr, colbuf, dinv, bg[l], Ch, N);
        cur = Ch;
    }

    // ---- MLP head ----
    gemm2h<false, true, true, true><<<dim3(M0 / 128, Npad / 64), 256, 0, stream>>>(
        Ch, Wm0T, bm0, nullptr, nullptr, Mh, N, HID, M0);
    gemm2h<false, true, true, false><<<dim3(M1 / 128, Npad / 64), 256, 0, stream>>>(
        Mh, Wm1T, bm1, nullptr, out, nullptr, N, M0, M1);
}

// Round 10
// 397.600 us; speedup vs baseline: 1.8154x; 1.0010x over previous
//
#include <hip/hip_runtime.h>

#define HID 128

typedef _Float16 half8 __attribute__((ext_vector_type(8)));
typedef _Float16 half4h __attribute__((ext_vector_type(4)));
using float4v = __attribute__((ext_vector_type(4))) float;

// ---- async global->LDS, 16 B per lane (wave-uniform base + lane*16) ----
typedef const __attribute__((address_space(1))) unsigned int* gas_ptr;
typedef __attribute__((address_space(3))) unsigned int* las_ptr;
__device__ __forceinline__ void gld16(const void* g, void* l) {
    __builtin_amdgcn_global_load_lds((gas_ptr)g, (las_ptr)l, 16, 0, 0);
}

// all 5 weight matrices transposed+converted: Wh[m*K+k] = W[k*M+m]
struct WSegs {
    const float* W[5];
    _Float16* H[5];
    int K[5], M[5], start[5];
};

// ---------------- FUSED1: deg count + x->fp16 + W transpose/convert ----------------
// blocks [0, nDeg): degree count; [nDeg, nDeg+nX): xconv; rest: wconv.
__global__ __launch_bounds__(256) void fused_prep1(
    const int* __restrict__ dst, int* __restrict__ degi, int E, int nDeg,
    const float* __restrict__ x, _Float16* __restrict__ Xh, int total4, int nX,
    WSegs S, int totalW) {
    int bx = blockIdx.x;
    if (bx < nDeg) {
        int i = bx * 256 + (int)threadIdx.x;
        if (i < E) atomicAdd(&degi[dst[i]], 1);
    } else if (bx < nDeg + nX) {
        int i = (bx - nDeg) * 256 + (int)threadIdx.x;
        if (i >= total4) return;
        const float4 v = *(const float4*)(x + (size_t)i * 4);
        half4h h;
        h.x = (_Float16)v.x; h.y = (_Float16)v.y; h.z = (_Float16)v.z; h.w = (_Float16)v.w;
        *(half4h*)(Xh + (size_t)i * 4) = h;
    } else {
        int idx = (bx - nDeg - nX) * 256 + (int)threadIdx.x;
        if (idx >= totalW) return;
        int s = 0;
#pragma unroll
        for (int t = 1; t < 5; ++t)
            if (idx >= S.start[t]) s = t;
        int local = idx - S.start[s];
        int M = S.M[s], K = S.K[s];
        int k = local / M;
        int m = local - k * M;
        S.H[s][(size_t)m * K + k] = (_Float16)S.W[s][local];
    }
}

// ---------------- prep2: unordered CSR base allocation (wave-scan + 1 atomic/wave) ----------------
// rowbeg/rowend need not be sorted — any disjoint contiguous ranges of size deg work.
__global__ __launch_bounds__(256) void prep2_kernel(
    const int* __restrict__ degi, int* __restrict__ rowbeg, int* __restrict__ rowend,
    int* __restrict__ cursor, float* __restrict__ dinv, int* __restrict__ tot, int N) {
    int i = blockIdx.x * 256 + (int)threadIdx.x;
    int lane = (int)threadIdx.x & 63;
    int d = (i < N) ? degi[i] : 0;
    int incl = d;
#pragma unroll
    for (int off = 1; off < 64; off <<= 1) {
        int t = __shfl_up(incl, off, 64);
        if (lane >= off) incl += t;
    }
    int wsum = __shfl(incl, 63, 64);
    int wbase = 0;
    if (lane == 63) wbase = atomicAdd(tot, wsum);
    wbase = __shfl(wbase, 63, 64);
    if (i < N) {
        int b = wbase + incl - d;
        rowbeg[i] = b;
        rowend[i] = b + d;
        cursor[i] = b;
        dinv[i] = rsqrtf((float)d + 1.0f);
    }
}

// ---------------- fp16 MFMA GEMM body: single-barrier double-buffered K-loop ----------------
// C[N x M] = epilogue(A[N x K] @ W[K x M]); A = fp16 [Npad][K], W = fp16 transposed [M][K].
// BM=64, BN=128, BK=32. 4 waves, each 64x32 (TM=4, TN=2). fp32 accumulate.
// Per-buffer LDS (halves): A[2048] B[4096] = 6144 (12 KB); dbuf 24 KB.
template <bool SCALE, bool BIAS, bool RELU, bool OUTHALF>
__device__ __forceinline__ void gemm_body(
    int bxc, int byr, const _Float16* __restrict__ Ah, const _Float16* __restrict__ Bh,
    const float* __restrict__ bias, const float* __restrict__ rowscale,
    float* __restrict__ outF, _Float16* __restrict__ outH, int Nout, int K, int M,
    _Float16* lds) {
    const int tid = threadIdx.x;
    const int bm = byr * 64;
    const int bn = bxc * 128;
    const int wave = tid >> 6, lane = tid & 63;
    const int quad = lane >> 4, c16 = lane & 15;
    const int wn = wave * 32;

    float4v acc[4][2];
#pragma unroll
    for (int a = 0; a < 4; ++a)
#pragma unroll
        for (int b = 0; b < 2; ++b)
#pragma unroll
            for (int r = 0; r < 4; ++r) acc[a][b][r] = 0.0f;

    const int r0 = tid >> 2;            // 0..63
    const int kq0 = (tid & 3) * 8;      // 0,8,16,24 (halves)

    const _Float16* gA  = Ah + (size_t)(bm + r0) * K + kq0;
    const _Float16* gB0 = Bh + (size_t)(bn + r0) * K + kq0;
    const _Float16* gB1 = Bh + (size_t)(bn + r0 + 64) * K + kq0;

    auto issue = [&](int c) {
        _Float16* buf = lds + (size_t)(c & 1) * 6144;
        int k0 = c * 32;
        gld16(gA + k0, buf + (size_t)tid * 8);
        gld16(gB0 + k0, buf + 2048 + (size_t)tid * 8);
        gld16(gB1 + k0, buf + 2048 + (size_t)(tid + 256) * 8);
    };

    issue(0);
    __syncthreads();

    const int nch = K >> 5;
    for (int c = 0; c < nch; ++c) {
        if (c + 1 < nch) issue(c + 1);  // DMA next chunk into other buffer

        const _Float16* buf = lds + (size_t)(c & 1) * 6144;
        half8 af[4], bf[2];
#pragma unroll
        for (int t = 0; t < 4; ++t)
            af[t] = *(const half8*)&buf[(t * 16 + c16) * 32 + quad * 8];
#pragma unroll
        for (int t = 0; t < 2; ++t)
            bf[t] = *(const half8*)&buf[2048 + (wn + t * 16 + c16) * 32 + quad * 8];
#pragma unroll
        for (int tm = 0; tm < 4; ++tm)
#pragma unroll
            for (int tn = 0; tn < 2; ++tn)
                acc[tm][tn] = __builtin_amdgcn_mfma_f32_16x16x32_f16(af[tm], bf[tn], acc[tm][tn], 0, 0, 0);
        __syncthreads();
    }

    // epilogue: C/D layout col=lane&15, row=quad*4+reg
#pragma unroll
    for (int tm = 0; tm < 4; ++tm) {
#pragma unroll
        for (int tn = 0; tn < 2; ++tn) {
            int colg = bn + wn + tn * 16 + c16;
            float bv = BIAS ? bias[colg] : 0.0f;
#pragma unroll
            for (int r = 0; r < 4; ++r) {
                int row = bm + tm * 16 + quad * 4 + r;
                if (row >= Nout) continue;
                float v = acc[tm][tn][r];
                if (SCALE) v *= rowscale[row];
                if (BIAS) v += bv;
                if (RELU) v = fmaxf(v, 0.0f);
                if (OUTHALF) outH[(size_t)row * M + colg] = (_Float16)v;
                else         outF[(size_t)row * M + colg] = v;
            }
        }
    }
}

template <bool SCALE, bool BIAS, bool RELU, bool OUTHALF>
__global__ __launch_bounds__(256, 4) void gemm_std(
    const _Float16* __restrict__ Ah, const _Float16* __restrict__ Bh,
    const float* __restrict__ bias, const float* __restrict__ rowscale,
    float* __restrict__ outF, _Float16* __restrict__ outH, int Nout, int K, int M) {
    __shared__ _Float16 lds[2 * 6144];
    gemm_body<SCALE, BIAS, RELU, OUTHALF>(blockIdx.x, blockIdx.y, Ah, Bh, bias, rowscale,
                                          outF, outH, Nout, K, M, lds);
}

// ---------------- FUSED2: CSR fill + layer-0 GEMM in one dispatch ----------------
// Fill is atomic/scattered-write-bound with all compute pipes idle; the GEMM is
// MFMA-bound. Heterogeneous blocks co-schedule on each CU (disjoint pipes).
__global__ __launch_bounds__(256, 4) void fill_gemm_kernel(
    const int* __restrict__ src, const int* __restrict__ dst,
    int* __restrict__ cursor, int* __restrict__ col, int E, int nFill,
    const _Float16* __restrict__ Ah, const _Float16* __restrict__ Bh,
    const float* __restrict__ rowscale, _Float16* __restrict__ outH,
    int Nout, int K, int M) {
    __shared__ _Float16 lds[2 * 6144];
    int bx = blockIdx.x;
    if (bx < nFill) {
        int e = bx * 256 + (int)threadIdx.x;
        if (e < E) {
            int d = dst[e];
            int pos = atomicAdd(&cursor[d], 1);
            col[pos] = src[e];
        }
    } else {
        gemm_body<true, false, false, true>(0, bx - nFill, Ah, Bh, nullptr, rowscale,
                                            nullptr, outH, Nout, K, M, lds);
    }
}

// ---------------- fused gather-reduce + finalize (fp16, fp32 accumulate) ----------------
// 16 lanes per node, 8 halves (16 B) per lane -> 256 B row per neighbor per 16-lane group.
__global__ __launch_bounds__(256) void gather_kernel(
    const _Float16* __restrict__ hs, const int* __restrict__ rowbeg,
    const int* __restrict__ rowend, const int* __restrict__ col,
    const float* __restrict__ dinv, const float* __restrict__ bias,
    _Float16* __restrict__ Ch, int N) {
    long long idx = (long long)blockIdx.x * blockDim.x + threadIdx.x;
    int i = (int)(idx >> 4);
    if (i >= N) return;
    int c = ((int)idx & 15) * 8;

    int beg = rowbeg[i];
    int end = rowend[i];

    const half8 sv = *(const half8*)(hs + (size_t)i * HID + c);  // self-loop
    float ax[8];
#pragma unroll
    for (int r = 0; r < 8; ++r) ax[r] = (float)sv[r];

    int j = beg;
    for (; j + 4 <= end; j += 4) {
        int s0 = col[j], s1 = col[j + 1], s2 = col[j + 2], s3 = col[j + 3];
        const half8 v0 = *(const half8*)(hs + (size_t)s0 * HID + c);
        const half8 v1 = *(const half8*)(hs + (size_t)s1 * HID + c);
        const half8 v2 = *(const half8*)(hs + (size_t)s2 * HID + c);
        const half8 v3 = *(const half8*)(hs + (size_t)s3 * HID + c);
#pragma unroll
        for (int r = 0; r < 8; ++r)
            ax[r] += ((float)v0[r] + (float)v1[r]) + ((float)v2[r] + (float)v3[r]);
    }
    for (; j < end; ++j) {
        int s = col[j];
        const half8 v = *(const half8*)(hs + (size_t)s * HID + c);
#pragma unroll
        for (int r = 0; r < 8; ++r) ax[r] += (float)v[r];
    }

    float di = dinv[i];
    half8 rr;
#pragma unroll
    for (int r = 0; r < 8; ++r)
        rr[r] = (_Float16)fmaxf(ax[r] * di + bias[c + r], 0.0f);
    *(half8*)(Ch + (size_t)i * HID + c) = rr;
}

// ---------------- host launch ----------------

extern "C" void kernel_launch(void* const* d_in, const int* in_sizes, int n_in,
                              void* d_out, int out_size, void* d_ws, size_t ws_size,
                              hipStream_t stream) {
    const float* x   = (const float*)d_in[0];
    const int*   ei  = (const int*)d_in[1];
    const float* Wg0 = (const float*)d_in[2];
    const float* bg0 = (const float*)d_in[3];
    const float* Wg1 = (const float*)d_in[4];
    const float* bg1 = (const float*)d_in[5];
    const float* Wg2 = (const float*)d_in[6];
    const float* bg2 = (const float*)d_in[7];
    const float* Wm0 = (const float*)d_in[8];
    const float* bm0 = (const float*)d_in[9];
    const float* Wm1 = (const float*)d_in[10];
    const float* bm1 = (const float*)d_in[11];
    float* out = (float*)d_out;

    const int N  = in_sizes[0] / HID;   // 50000
    const int E  = in_sizes[1] / 2;     // 800000
    const int M0 = in_sizes[9];         // 512
    const int M1 = in_sizes[11];        // 256
    const int Npad = ((N + 127) / 128) * 128;   // 50048

    const int* src = ei;
    const int* dst = ei + E;

    char* ws = (char*)d_ws;
    size_t off = 0;
    auto alloc = [&](size_t bytes) {
        void* p = ws + off;
        off += (bytes + 255) & ~(size_t)255;
        return p;
    };
    int* degi   = (int*)alloc((size_t)N * 4);
    int* tot    = (int*)alloc(256);            // adjacent to degi's padded end
    int* rowbeg = (int*)alloc((size_t)N * 4);
    int* rowend = (int*)alloc((size_t)N * 4);
    int* cursor = (int*)alloc((size_t)N * 4);
    int* colbuf = (int*)alloc((size_t)E * 4);
    float* dinv = (float*)alloc((size_t)N * 4);
    _Float16* WgT[3];
    for (int l = 0; l < 3; ++l)
        WgT[l] = (_Float16*)alloc((size_t)HID * HID * 2);
    _Float16* Wm0T = (_Float16*)alloc((size_t)M0 * HID * 2);
    _Float16* Wm1T = (_Float16*)alloc((size_t)M1 * M0 * 2);
    _Float16* Xh = (_Float16*)alloc((size_t)Npad * HID * 2);   // fp16 input plane
    _Float16* Hs = (_Float16*)alloc((size_t)Npad * HID * 2);   // GEMM out / gather in
    _Float16* Ch = (_Float16*)alloc((size_t)Npad * HID * 2);   // gather out
    _Float16* Mh = (_Float16*)alloc((size_t)Npad * M0 * 2);    // MLP hidden

    // zero degi + tot in one memset (they are adjacent in the workspace)
    hipMemsetAsync(degi, 0, ((char*)tot - (char*)degi) + 256, stream);

    // ---- FUSED1: deg + xconv + wconv ----
    const int nDeg = (E + 255) / 256;               // 3125
    const int total4 = N * HID / 4;
    const int nX = (total4 + 255) / 256;            // 6250
    int totalW;
    WSegs S;
    {
        const float* Ws[5] = {Wg0, Wg1, Wg2, Wm0, Wm1};
        _Float16* Hs5[5]   = {WgT[0], WgT[1], WgT[2], Wm0T, Wm1T};
        int Ks[5] = {HID, HID, HID, HID, M0};
        int Ms[5] = {HID, HID, HID, M0, M1};
        int start = 0;
        for (int s = 0; s < 5; ++s) {
            S.W[s] = Ws[s]; S.H[s] = Hs5[s];
            S.K[s] = Ks[s]; S.M[s] = Ms[s]; S.start[s] = start;
            start += Ks[s] * Ms[s];
        }
        totalW = start;
    }
    const int nW = (totalW + 255) / 256;
    fused_prep1<<<nDeg + nX + nW, 256, 0, stream>>>(
        dst, degi, E, nDeg, x, Xh, total4, nX, S, totalW);

    // ---- prep2: unordered CSR bases + dinv ----
    prep2_kernel<<<(N + 255) / 256, 256, 0, stream>>>(
        degi, rowbeg, rowend, cursor, dinv, tot, N);

    // ---- FUSED2: fill + layer-0 GEMM ----
    fill_gemm_kernel<<<nDeg + Npad / 64, 256, 0, stream>>>(
        src, dst, cursor, colbuf, E, nDeg,
        Xh, WgT[0], dinv, Hs, N, HID, HID);

    // ---- layer 0 gather, then layers 1,2 ----
    const float* bg[3] = {bg0, bg1, bg2};
    long long gatherThreads = (long long)N * 16;
    int gblocks = (int)((gatherThreads + 255) / 256);
    gather_kernel<<<gblocks, 256, 0, stream>>>(
        Hs, rowbeg, rowend, colbuf, dinv, bg[0], Ch, N);
    for (int l = 1; l < 3; ++l) {
        gemm_std<true, false, false, true><<<dim3(1, Npad / 64), 256, 0, stream>>>(
            Ch, WgT[l], nullptr, dinv, nullptr, Hs, N, HID, HID);
        gather_kernel<<<gblocks, 256, 0, stream>>>(
            Hs, rowbeg, rowend, colbuf, dinv, bg[l], Ch, N);
    }

    // ---- MLP head ----
    gemm_std<false, true, true, true><<<dim3(M0 / 128, Npad / 64), 256, 0, stream>>>(
        Ch, Wm0T, bm0, nullptr, nullptr, Mh, N, HID, M0);
    gemm_std<false, true, true, false><<<dim3(M1 / 128, Npad / 64), 256, 0, stream>>>(
        Mh, Wm1T, bm1, nullptr, out, nullptr, N, M0, M1);
}